// Round 1
// baseline (315.992 us; speedup 1.0000x reference)
//
#include <hip/hip_runtime.h>
#include <math.h>

#define SLOPE 0.01f

// ---------------------------------------------------------------
// A = x @ W1[0:128,:],  B = x @ W1[128:256,:]   (B written to d_out)
// 8 rows per block, 128 threads (one output column each)
// ---------------------------------------------------------------
__global__ __launch_bounds__(128) void gemm_ab(
    const float* __restrict__ x, const float* __restrict__ W1,
    float* __restrict__ A, float* __restrict__ Bm, int n_nodes) {
  __shared__ float xs[8][128];
  int row0 = blockIdx.x * 8;
  int d = threadIdx.x;
  #pragma unroll
  for (int r = 0; r < 8; ++r) {
    int n = row0 + r;
    xs[r][d] = (n < n_nodes) ? x[(size_t)n * 128 + d] : 0.f;
  }
  __syncthreads();
  float accA[8] = {0.f,0.f,0.f,0.f,0.f,0.f,0.f,0.f};
  float accB[8] = {0.f,0.f,0.f,0.f,0.f,0.f,0.f,0.f};
  for (int k = 0; k < 128; k += 4) {
    float wa0 = W1[(k+0)*128 + d];
    float wa1 = W1[(k+1)*128 + d];
    float wa2 = W1[(k+2)*128 + d];
    float wa3 = W1[(k+3)*128 + d];
    float wb0 = W1[(128+k+0)*128 + d];
    float wb1 = W1[(128+k+1)*128 + d];
    float wb2 = W1[(128+k+2)*128 + d];
    float wb3 = W1[(128+k+3)*128 + d];
    #pragma unroll
    for (int r = 0; r < 8; ++r) {
      float4 xv = *(const float4*)&xs[r][k];
      accA[r] = fmaf(xv.x, wa0, accA[r]);
      accA[r] = fmaf(xv.y, wa1, accA[r]);
      accA[r] = fmaf(xv.z, wa2, accA[r]);
      accA[r] = fmaf(xv.w, wa3, accA[r]);
      accB[r] = fmaf(xv.x, wb0, accB[r]);
      accB[r] = fmaf(xv.y, wb1, accB[r]);
      accB[r] = fmaf(xv.z, wb2, accB[r]);
      accB[r] = fmaf(xv.w, wb3, accB[r]);
    }
  }
  #pragma unroll
  for (int r = 0; r < 8; ++r) {
    int n = row0 + r;
    if (n < n_nodes) {
      A[(size_t)n * 128 + d]  = accA[r];
      Bm[(size_t)n * 128 + d] = accB[r];
    }
  }
}

// ---------------------------------------------------------------
// Crel[r] = rel[r] @ W1[256:384,:] + b1 ;  pC[r] = Crel[r] . w2
// ---------------------------------------------------------------
__global__ __launch_bounds__(128) void crel_kernel(
    const float* __restrict__ rel, const float* __restrict__ W1,
    const float* __restrict__ b1, const float* __restrict__ w2,
    float* __restrict__ Crel, float* __restrict__ pC) {
  __shared__ float rs[128];
  __shared__ float red[128];
  int r = blockIdx.x;
  int d = threadIdx.x;
  rs[d] = rel[r * 128 + d];
  __syncthreads();
  float acc = b1[d];
  for (int k = 0; k < 128; ++k)
    acc = fmaf(rs[k], W1[(256 + k) * 128 + d], acc);
  Crel[r * 128 + d] = acc;
  red[d] = acc * w2[d];
  __syncthreads();
  for (int s = 64; s > 0; s >>= 1) {
    if (d < s) red[d] += red[d + s];
    __syncthreads();
  }
  if (d == 0) pC[r] = red[0];
}

// ---------------------------------------------------------------
// pA[n] = A[n].w2 ; pB[n] = B[n].w2   (one wave per node)
// ---------------------------------------------------------------
__global__ __launch_bounds__(256) void dotw2(
    const float* __restrict__ A, const float* Bm, const float* __restrict__ w2,
    float* __restrict__ pA, float* __restrict__ pB, int n_nodes) {
  int wid = (blockIdx.x * 256 + threadIdx.x) >> 6;
  int lane = threadIdx.x & 63;
  if (wid >= n_nodes) return;
  float w0 = w2[lane], w1 = w2[lane + 64];
  size_t base = (size_t)wid * 128;
  float sA = A[base + lane] * w0 + A[base + 64 + lane] * w1;
  float sB = Bm[base + lane] * w0 + Bm[base + 64 + lane] * w1;
  #pragma unroll
  for (int s = 32; s; s >>= 1) {
    sA += __shfl_xor(sA, s, 64);
    sB += __shfl_xor(sB, s, 64);
  }
  if (lane == 0) { pA[wid] = sA; pB[wid] = sB; }
}

// ---------------------------------------------------------------
// CSR build: histogram, exclusive scan, permutation fill
// ---------------------------------------------------------------
__global__ void hist_kernel(const int* __restrict__ dsts, int* __restrict__ deg, int E) {
  int i = blockIdx.x * 256 + threadIdx.x;
  if (i < E) atomicAdd(&deg[dsts[i]], 1);
}

__global__ __launch_bounds__(1024) void scan_kernel(
    const int* __restrict__ deg, int* __restrict__ off, int* __restrict__ pos, int n) {
  __shared__ int sdata[1024];
  __shared__ int carry_s;
  int t = threadIdx.x;
  if (t == 0) carry_s = 0;
  __syncthreads();
  for (int base = 0; base < n; base += 1024) {
    int i = base + t;
    int v = (i < n) ? deg[i] : 0;
    sdata[t] = v;
    __syncthreads();
    for (int sft = 1; sft < 1024; sft <<= 1) {
      int add = (t >= sft) ? sdata[t - sft] : 0;
      __syncthreads();
      sdata[t] += add;
      __syncthreads();
    }
    int carry = carry_s;
    if (i < n) {
      int excl = carry + sdata[t] - v;
      off[i] = excl;
      pos[i] = excl;
    }
    __syncthreads();
    if (t == 1023) carry_s = carry + sdata[1023];
    __syncthreads();
  }
}

__global__ void fill_perm(const int* __restrict__ dsts, int* __restrict__ pos,
                          int* __restrict__ perm, int E) {
  int i = blockIdx.x * 256 + threadIdx.x;
  if (i < E) {
    int p = atomicAdd(&pos[dsts[i]], 1);
    perm[p] = i;
  }
}

// ---------------------------------------------------------------
// Per-node softmax + weighted gather. One wave (64 threads) per node.
// out[n] = lrelu( sum_e alpha_e (A[src_e]+Crel[type_e]) + B[n] )
// (B aliases out: read before write within the same thread)
// ---------------------------------------------------------------
__global__ __launch_bounds__(64) void aggregate(
    const int* __restrict__ srcs, const int* __restrict__ types,
    const int* __restrict__ off, const int* __restrict__ deg,
    const int* __restrict__ perm,
    const float* __restrict__ pA, const float* __restrict__ pB,
    const float* __restrict__ pC,
    const float* __restrict__ A, const float* Bm,
    const float* __restrict__ Crel,
    float* out, int n_nodes) {
  int n = blockIdx.x;
  if (n >= n_nodes) return;
  int lane = threadIdx.x;
  int start = off[n];
  int dcnt = deg[n];
  size_t obase = (size_t)n * 128;
  if (dcnt == 0) {
    out[obase + lane] = 0.f;
    out[obase + 64 + lane] = 0.f;
    return;
  }
  float pBn = pB[n];
  // pass 1: max logit (lanes stride over edges)
  float m = -1e30f;
  for (int i = lane; i < dcnt; i += 64) {
    int e = perm[start + i];
    int s = srcs[e], t = types[e];
    float b = pA[s] + pBn + pC[t];
    b = b > 0.f ? b : SLOPE * b;
    m = fmaxf(m, b);
  }
  #pragma unroll
  for (int s = 32; s; s >>= 1) m = fmaxf(m, __shfl_xor(m, s, 64));
  // pass 2: exp + weighted accumulation (all lanes cooperate per edge)
  float acc0 = 0.f, acc1 = 0.f, S = 0.f;
  for (int i = 0; i < dcnt; ++i) {
    int e = perm[start + i];
    int s = srcs[e], t = types[e];
    float b = pA[s] + pBn + pC[t];
    b = b > 0.f ? b : SLOPE * b;
    float ex = __expf(b - m);
    S += ex;
    size_t abase = (size_t)s * 128;
    int cbase = t * 128;
    acc0 = fmaf(ex, A[abase + lane] + Crel[cbase + lane], acc0);
    acc1 = fmaf(ex, A[abase + 64 + lane] + Crel[cbase + 64 + lane], acc1);
  }
  float inv = 1.f / S;
  float o0 = acc0 * inv + Bm[obase + lane];
  float o1 = acc1 * inv + Bm[obase + 64 + lane];
  out[obase + lane]      = o0 > 0.f ? o0 : SLOPE * o0;
  out[obase + 64 + lane] = o1 > 0.f ? o1 : SLOPE * o1;
}

extern "C" void kernel_launch(void* const* d_in, const int* in_sizes, int n_in,
                              void* d_out, int out_size, void* d_ws, size_t ws_size,
                              hipStream_t stream) {
  const float* x    = (const float*)d_in[0];
  const float* rel  = (const float*)d_in[1];
  const float* W1   = (const float*)d_in[2];
  const float* b1   = (const float*)d_in[3];
  const float* w2   = (const float*)d_in[4];
  const int* edge_index = (const int*)d_in[5];
  const int* edge_type  = (const int*)d_in[6];

  int n_nodes = in_sizes[0] / 128;
  int n_rel   = in_sizes[1] / 128;
  int E       = in_sizes[6];
  const int* srcs = edge_index;
  const int* dsts = edge_index + E;
  float* out = (float*)d_out;

  // workspace layout (B lives in d_out)
  char* ws = (char*)d_ws;
  float* A    = (float*)ws; ws += (size_t)n_nodes * 128 * 4;
  float* Crel = (float*)ws; ws += (size_t)n_rel * 128 * 4;
  float* pA   = (float*)ws; ws += (size_t)n_nodes * 4;
  float* pB   = (float*)ws; ws += (size_t)n_nodes * 4;
  float* pC   = (float*)ws; ws += (size_t)n_rel * 4;
  int* deg    = (int*)ws;   ws += (size_t)n_nodes * 4;
  int* off    = (int*)ws;   ws += (size_t)n_nodes * 4;
  int* pos    = (int*)ws;   ws += (size_t)n_nodes * 4;
  int* perm   = (int*)ws;   ws += (size_t)E * 4;
  float* Bm   = out;  // B stored directly in output buffer

  hipMemsetAsync(deg, 0, (size_t)n_nodes * 4, stream);

  gemm_ab<<<(n_nodes + 7) / 8, 128, 0, stream>>>(x, W1, A, Bm, n_nodes);
  crel_kernel<<<n_rel, 128, 0, stream>>>(rel, W1, b1, w2, Crel, pC);
  dotw2<<<(n_nodes + 3) / 4, 256, 0, stream>>>(A, Bm, w2, pA, pB, n_nodes);
  hist_kernel<<<(E + 255) / 256, 256, 0, stream>>>(dsts, deg, E);
  scan_kernel<<<1, 1024, 0, stream>>>(deg, off, pos, n_nodes);
  fill_perm<<<(E + 255) / 256, 256, 0, stream>>>(dsts, pos, perm, E);
  aggregate<<<n_nodes, 64, 0, stream>>>(srcs, edge_type, off, deg, perm,
                                        pA, pB, pC, A, Bm, Crel, out, n_nodes);
}

// Round 2
// 214.856 us; speedup vs baseline: 1.4707x; 1.4707x over previous
//
#include <hip/hip_runtime.h>
#include <math.h>

#define SLOPE 0.01f

// ---------------------------------------------------------------
// A = x @ W1[0:128,:],  B = x @ W1[128:256,:]   (B written to d_out)
// Also fused: pA[n] = A[n].w2 ; pB[n] = B[n].w2
// 16 rows per block, 128 threads (one output column each)
// ---------------------------------------------------------------
#define GROWS 16
__global__ __launch_bounds__(128) void gemm_ab(
    const float* __restrict__ x, const float* __restrict__ W1,
    const float* __restrict__ w2,
    float* __restrict__ A, float* __restrict__ Bm,
    float* __restrict__ pA, float* __restrict__ pB, int n_nodes) {
  __shared__ float xs[GROWS][128];
  int row0 = blockIdx.x * GROWS;
  int d = threadIdx.x;
  #pragma unroll
  for (int r = 0; r < GROWS; ++r) {
    int n = row0 + r;
    xs[r][d] = (n < n_nodes) ? x[(size_t)n * 128 + d] : 0.f;
  }
  __syncthreads();
  float accA[GROWS], accB[GROWS];
  #pragma unroll
  for (int r = 0; r < GROWS; ++r) { accA[r] = 0.f; accB[r] = 0.f; }
  for (int k = 0; k < 128; k += 4) {
    float wa0 = W1[(k+0)*128 + d];
    float wa1 = W1[(k+1)*128 + d];
    float wa2 = W1[(k+2)*128 + d];
    float wa3 = W1[(k+3)*128 + d];
    float wb0 = W1[(128+k+0)*128 + d];
    float wb1 = W1[(128+k+1)*128 + d];
    float wb2 = W1[(128+k+2)*128 + d];
    float wb3 = W1[(128+k+3)*128 + d];
    #pragma unroll
    for (int r = 0; r < GROWS; ++r) {
      float4 xv = *(const float4*)&xs[r][k];
      accA[r] = fmaf(xv.x, wa0, accA[r]);
      accA[r] = fmaf(xv.y, wa1, accA[r]);
      accA[r] = fmaf(xv.z, wa2, accA[r]);
      accA[r] = fmaf(xv.w, wa3, accA[r]);
      accB[r] = fmaf(xv.x, wb0, accB[r]);
      accB[r] = fmaf(xv.y, wb1, accB[r]);
      accB[r] = fmaf(xv.z, wb2, accB[r]);
      accB[r] = fmaf(xv.w, wb3, accB[r]);
    }
  }
  #pragma unroll
  for (int r = 0; r < GROWS; ++r) {
    int n = row0 + r;
    if (n < n_nodes) {
      A[(size_t)n * 128 + d]  = accA[r];
      Bm[(size_t)n * 128 + d] = accB[r];
    }
  }
  // fused pA = A.w2 (LDS tree reduce, 16 rows at once)
  float w2d = w2[d];
  __syncthreads();
  #pragma unroll
  for (int r = 0; r < GROWS; ++r) xs[r][d] = accA[r] * w2d;
  __syncthreads();
  for (int s = 64; s > 0; s >>= 1) {
    if (d < s) {
      #pragma unroll
      for (int r = 0; r < GROWS; ++r) xs[r][d] += xs[r][d + s];
    }
    __syncthreads();
  }
  if (d < GROWS && row0 + d < n_nodes) pA[row0 + d] = xs[d][0];
  __syncthreads();
  #pragma unroll
  for (int r = 0; r < GROWS; ++r) xs[r][d] = accB[r] * w2d;
  __syncthreads();
  for (int s = 64; s > 0; s >>= 1) {
    if (d < s) {
      #pragma unroll
      for (int r = 0; r < GROWS; ++r) xs[r][d] += xs[r][d + s];
    }
    __syncthreads();
  }
  if (d < GROWS && row0 + d < n_nodes) pB[row0 + d] = xs[d][0];
}

// ---------------------------------------------------------------
// Crel[r] = rel[r] @ W1[256:384,:] + b1 ;  pC[r] = Crel[r] . w2
// ---------------------------------------------------------------
__global__ __launch_bounds__(128) void crel_kernel(
    const float* __restrict__ rel, const float* __restrict__ W1,
    const float* __restrict__ b1, const float* __restrict__ w2,
    float* __restrict__ Crel, float* __restrict__ pC) {
  __shared__ float rs[128];
  __shared__ float red[128];
  int r = blockIdx.x;
  int d = threadIdx.x;
  rs[d] = rel[r * 128 + d];
  __syncthreads();
  float acc = b1[d];
  for (int k = 0; k < 128; ++k)
    acc = fmaf(rs[k], W1[(256 + k) * 128 + d], acc);
  Crel[r * 128 + d] = acc;
  red[d] = acc * w2[d];
  __syncthreads();
  for (int s = 64; s > 0; s >>= 1) {
    if (d < s) red[d] += red[d + s];
    __syncthreads();
  }
  if (d == 0) pC[r] = red[0];
}

// ---------------------------------------------------------------
// CSR build: histogram -> 3-stage scan -> permutation fill w/ logits
// ---------------------------------------------------------------
__global__ void hist_kernel(const int* __restrict__ dsts, int* __restrict__ deg, int E) {
  int i = blockIdx.x * 256 + threadIdx.x;
  if (i < E) atomicAdd(&deg[dsts[i]], 1);
}

__global__ __launch_bounds__(1024) void scan1(
    const int* __restrict__ deg, int* __restrict__ off,
    int* __restrict__ partial, int n) {
  __shared__ int sdata[1024];
  int t = threadIdx.x;
  int i = blockIdx.x * 1024 + t;
  int v = (i < n) ? deg[i] : 0;
  sdata[t] = v;
  __syncthreads();
  for (int s = 1; s < 1024; s <<= 1) {
    int add = (t >= s) ? sdata[t - s] : 0;
    __syncthreads();
    sdata[t] += add;
    __syncthreads();
  }
  if (i < n) off[i] = sdata[t] - v;          // block-local exclusive
  if (t == 1023) partial[blockIdx.x] = sdata[1023];
}

__global__ __launch_bounds__(1024) void scan2(int* __restrict__ partial, int nb) {
  __shared__ int sdata[1024];
  int t = threadIdx.x;
  int v = (t < nb) ? partial[t] : 0;
  sdata[t] = v;
  __syncthreads();
  for (int s = 1; s < 1024; s <<= 1) {
    int add = (t >= s) ? sdata[t - s] : 0;
    __syncthreads();
    sdata[t] += add;
    __syncthreads();
  }
  if (t < nb) partial[t] = sdata[t] - v;     // exclusive over partials
}

__global__ __launch_bounds__(1024) void scan3(
    int* __restrict__ off, int* __restrict__ pos,
    const int* __restrict__ partial, int n) {
  int i = blockIdx.x * 1024 + threadIdx.x;
  if (i < n) {
    int o = off[i] + partial[blockIdx.x];
    off[i] = o;
    pos[i] = o;
  }
}

// fill CSR slots with src, type, and precomputed leaky-relu'd logit
__global__ void fill_perm(
    const int* __restrict__ srcs, const int* __restrict__ dsts,
    const int* __restrict__ types,
    const float* __restrict__ pA, const float* __restrict__ pB,
    const float* __restrict__ pC,
    int* __restrict__ pos,
    int* __restrict__ sperm, int* __restrict__ tperm,
    float* __restrict__ bperm, int E) {
  int i = blockIdx.x * 256 + threadIdx.x;
  if (i < E) {
    int dn = dsts[i];
    int s  = srcs[i];
    int t  = types[i];
    float b = pA[s] + pB[dn] + pC[t];
    b = b > 0.f ? b : SLOPE * b;
    int p = atomicAdd(&pos[dn], 1);
    sperm[p] = s;
    tperm[p] = t;
    bperm[p] = b;
  }
}

// ---------------------------------------------------------------
// Per-node softmax + weighted gather. One wave per node, 4 nodes/block.
// out[n] = lrelu( sum_e alpha_e (A[src_e]+Crel[type_e]) + B[n] )
// ---------------------------------------------------------------
__global__ __launch_bounds__(256) void aggregate(
    const int* __restrict__ off, const int* __restrict__ deg,
    const int* __restrict__ sperm, const int* __restrict__ tperm,
    const float* __restrict__ bperm,
    const float* __restrict__ A, const float* Bm,
    const float* __restrict__ Crel,
    float* out, int n_nodes) {
  int n = blockIdx.x * 4 + (threadIdx.x >> 6);
  if (n >= n_nodes) return;
  int lane = threadIdx.x & 63;
  int start = off[n];
  int dcnt = deg[n];
  size_t obase = (size_t)n * 128;
  if (dcnt == 0) {
    out[obase + lane] = 0.f;
    out[obase + 64 + lane] = 0.f;
    return;
  }
  // pass 1: max over contiguous logits
  float m = -1e30f;
  for (int i = lane; i < dcnt; i += 64) m = fmaxf(m, bperm[start + i]);
  #pragma unroll
  for (int s = 32; s; s >>= 1) m = fmaxf(m, __shfl_xor(m, s, 64));
  // pass 2: exp + weighted accumulation, 2 edges in flight
  float acc0 = 0.f, acc1 = 0.f, S = 0.f;
  int i = 0;
  for (; i + 2 <= dcnt; i += 2) {
    int sa = sperm[start + i],     ta = tperm[start + i];
    int sb = sperm[start + i + 1], tb = tperm[start + i + 1];
    float exa = __expf(bperm[start + i] - m);
    float exb = __expf(bperm[start + i + 1] - m);
    const float* Aa = A + (size_t)sa * 128 + lane;
    const float* Ab = A + (size_t)sb * 128 + lane;
    const float* Ca = Crel + ta * 128 + lane;
    const float* Cb = Crel + tb * 128 + lane;
    float a0 = Aa[0], a1 = Aa[64];
    float b0 = Ab[0], b1 = Ab[64];
    float c0 = Ca[0], c1 = Ca[64];
    float d0 = Cb[0], d1 = Cb[64];
    S += exa + exb;
    acc0 = fmaf(exa, a0 + c0, acc0);
    acc1 = fmaf(exa, a1 + c1, acc1);
    acc0 = fmaf(exb, b0 + d0, acc0);
    acc1 = fmaf(exb, b1 + d1, acc1);
  }
  if (i < dcnt) {
    int sa = sperm[start + i], ta = tperm[start + i];
    float exa = __expf(bperm[start + i] - m);
    const float* Aa = A + (size_t)sa * 128 + lane;
    const float* Ca = Crel + ta * 128 + lane;
    S += exa;
    acc0 = fmaf(exa, Aa[0] + Ca[0], acc0);
    acc1 = fmaf(exa, Aa[64] + Ca[64], acc1);
  }
  float inv = 1.f / S;
  float o0 = acc0 * inv + Bm[obase + lane];
  float o1 = acc1 * inv + Bm[obase + 64 + lane];
  out[obase + lane]      = o0 > 0.f ? o0 : SLOPE * o0;
  out[obase + 64 + lane] = o1 > 0.f ? o1 : SLOPE * o1;
}

extern "C" void kernel_launch(void* const* d_in, const int* in_sizes, int n_in,
                              void* d_out, int out_size, void* d_ws, size_t ws_size,
                              hipStream_t stream) {
  const float* x    = (const float*)d_in[0];
  const float* rel  = (const float*)d_in[1];
  const float* W1   = (const float*)d_in[2];
  const float* b1   = (const float*)d_in[3];
  const float* w2   = (const float*)d_in[4];
  const int* edge_index = (const int*)d_in[5];
  const int* edge_type  = (const int*)d_in[6];

  int n_nodes = in_sizes[0] / 128;
  int n_rel   = in_sizes[1] / 128;
  int E       = in_sizes[6];
  const int* srcs = edge_index;
  const int* dsts = edge_index + E;
  float* out = (float*)d_out;

  // workspace layout (B lives in d_out)
  char* ws = (char*)d_ws;
  float* A     = (float*)ws; ws += (size_t)n_nodes * 128 * 4;
  float* Crel  = (float*)ws; ws += (size_t)n_rel * 128 * 4;
  float* pA    = (float*)ws; ws += (size_t)n_nodes * 4;
  float* pB    = (float*)ws; ws += (size_t)n_nodes * 4;
  float* pC    = (float*)ws; ws += (size_t)n_rel * 4;
  int* deg     = (int*)ws;   ws += (size_t)n_nodes * 4;
  int* off     = (int*)ws;   ws += (size_t)n_nodes * 4;
  int* pos     = (int*)ws;   ws += (size_t)n_nodes * 4;
  int* partial = (int*)ws;   ws += 1024 * 4;
  int* sperm   = (int*)ws;   ws += (size_t)E * 4;
  int* tperm   = (int*)ws;   ws += (size_t)E * 4;
  float* bperm = (float*)ws; ws += (size_t)E * 4;
  float* Bm    = out;  // B stored directly in output buffer

  hipMemsetAsync(deg, 0, (size_t)n_nodes * 4, stream);

  gemm_ab<<<(n_nodes + GROWS - 1) / GROWS, 128, 0, stream>>>(
      x, W1, w2, A, Bm, pA, pB, n_nodes);
  crel_kernel<<<n_rel, 128, 0, stream>>>(rel, W1, b1, w2, Crel, pC);
  hist_kernel<<<(E + 255) / 256, 256, 0, stream>>>(dsts, deg, E);
  int nb = (n_nodes + 1023) / 1024;
  scan1<<<nb, 1024, 0, stream>>>(deg, off, partial, n_nodes);
  scan2<<<1, 1024, 0, stream>>>(partial, nb);
  scan3<<<nb, 1024, 0, stream>>>(off, pos, partial, n_nodes);
  fill_perm<<<(E + 255) / 256, 256, 0, stream>>>(
      srcs, dsts, edge_type, pA, pB, pC, pos, sperm, tperm, bperm, E);
  aggregate<<<(n_nodes + 3) / 4, 256, 0, stream>>>(
      off, deg, sperm, tperm, bperm, A, Bm, Crel, out, n_nodes);
}

// Round 3
// 160.576 us; speedup vs baseline: 1.9679x; 1.3380x over previous
//
#include <hip/hip_runtime.h>
#include <math.h>

#define SLOPE 0.01f

using bf16x8 = __attribute__((ext_vector_type(8))) short;
using f32x4  = __attribute__((ext_vector_type(4))) float;

__device__ __forceinline__ unsigned short f2bf(float f) {
  unsigned int u = __float_as_uint(f);
  unsigned int r = 0x7FFFu + ((u >> 16) & 1u);
  return (unsigned short)((u + r) >> 16);
}
__device__ __forceinline__ float bflo(unsigned int v) {  // low ushort -> float
  return __uint_as_float(v << 16);
}
__device__ __forceinline__ float bfhi(unsigned int v) {  // high ushort -> float
  return __uint_as_float(v & 0xFFFF0000u);
}

// ---------------------------------------------------------------
// x fp32 -> bf16 (8 elements per thread)
// ---------------------------------------------------------------
__global__ __launch_bounds__(256) void conv_x(
    const float* __restrict__ x, unsigned short* __restrict__ xb, int total8) {
  int i = blockIdx.x * 256 + threadIdx.x;
  if (i >= total8) return;
  const float4* p = (const float4*)(x + (size_t)i * 8);
  float4 v0 = p[0], v1 = p[1];
  union { unsigned short us[8]; uint4 u4; } pk;
  pk.us[0] = f2bf(v0.x); pk.us[1] = f2bf(v0.y);
  pk.us[2] = f2bf(v0.z); pk.us[3] = f2bf(v0.w);
  pk.us[4] = f2bf(v1.x); pk.us[5] = f2bf(v1.y);
  pk.us[6] = f2bf(v1.z); pk.us[7] = f2bf(v1.w);
  *(uint4*)(xb + (size_t)i * 8) = pk.u4;
}

// ---------------------------------------------------------------
// WT[n][k] bf16 = W1[(n>=128?128:0)+k][n&127]   (256 x 128, tiny)
// ---------------------------------------------------------------
__global__ __launch_bounds__(128) void conv_w(
    const float* __restrict__ W1, unsigned short* __restrict__ WT) {
  int n = blockIdx.x;
  int k = threadIdx.x;
  int src_row = ((n >> 7) << 7) + k;  // +0 or +128
  WT[n * 128 + k] = f2bf(W1[src_row * 128 + (n & 127)]);
}

// ---------------------------------------------------------------
// MFMA GEMM: [A|B] = xb @ WT^T.  M=n_nodes, N=256 (y-half picks 128),
// K=128. Block = 4 waves, tile 64M x 128N; wave = 32M x 64N.
// Fused: pA[n] = A[n].w2, pB[n] = B[n].w2 (fp32 from accumulators).
// A stored bf16 (Abf), B stored fp32 into d_out (Bm).
// ---------------------------------------------------------------
__global__ __launch_bounds__(256) void gemm_mfma(
    const unsigned short* __restrict__ xb, const unsigned short* __restrict__ WT,
    const float* __restrict__ w2,
    unsigned short* __restrict__ Abf, float* __restrict__ Bm,
    float* __restrict__ pA, float* __restrict__ pB, int M) {
  __shared__ float ps[2][64];
  int tid  = threadIdx.x;
  int wave = tid >> 6, lane = tid & 63;
  int wm = wave >> 1, wn = wave & 1;
  int l15 = lane & 15, l4 = lane >> 4;
  int m0 = blockIdx.x * 64;
  int y  = blockIdx.y;

  f32x4 acc[2][4];
  #pragma unroll
  for (int mi = 0; mi < 2; ++mi)
    #pragma unroll
    for (int ni = 0; ni < 4; ++ni) acc[mi][ni] = (f32x4){0.f, 0.f, 0.f, 0.f};

  int arow0 = m0 + wm * 32 + l15;
  int arow1 = arow0 + 16;
  int ar0 = arow0 < M ? arow0 : M - 1;
  int ar1 = arow1 < M ? arow1 : M - 1;
  const unsigned short* abase0 = xb + (size_t)ar0 * 128 + l4 * 8;
  const unsigned short* abase1 = xb + (size_t)ar1 * 128 + l4 * 8;
  const unsigned short* bbase  = WT + (size_t)(y * 128 + wn * 64 + l15) * 128 + l4 * 8;

  #pragma unroll
  for (int ks = 0; ks < 4; ++ks) {
    bf16x8 af0 = *(const bf16x8*)(abase0 + ks * 32);
    bf16x8 af1 = *(const bf16x8*)(abase1 + ks * 32);
    #pragma unroll
    for (int ni = 0; ni < 4; ++ni) {
      bf16x8 bf = *(const bf16x8*)(bbase + ni * 16 * 128 + ks * 32);
      acc[0][ni] = __builtin_amdgcn_mfma_f32_16x16x32_bf16(af0, bf, acc[0][ni], 0, 0, 0);
      acc[1][ni] = __builtin_amdgcn_mfma_f32_16x16x32_bf16(af1, bf, acc[1][ni], 0, 0, 0);
    }
  }

  // stores: C/D layout col=lane&15, row=4*(lane>>4)+reg
  #pragma unroll
  for (int mi = 0; mi < 2; ++mi) {
    #pragma unroll
    for (int ni = 0; ni < 4; ++ni) {
      int coll = wn * 64 + ni * 16 + l15;
      #pragma unroll
      for (int r = 0; r < 4; ++r) {
        int row = m0 + wm * 32 + mi * 16 + l4 * 4 + r;
        if (row < M) {
          if (y == 0) Abf[(size_t)row * 128 + coll] = f2bf(acc[mi][ni][r]);
          else        Bm[(size_t)row * 128 + coll]  = acc[mi][ni][r];
        }
      }
    }
  }

  // fused dot with w2
  float w2c[4];
  #pragma unroll
  for (int ni = 0; ni < 4; ++ni) w2c[ni] = w2[wn * 64 + ni * 16 + l15];
  float pd[2][4];
  #pragma unroll
  for (int mi = 0; mi < 2; ++mi)
    #pragma unroll
    for (int r = 0; r < 4; ++r) {
      float v = 0.f;
      #pragma unroll
      for (int ni = 0; ni < 4; ++ni) v = fmaf(acc[mi][ni][r], w2c[ni], v);
      #pragma unroll
      for (int s = 1; s < 16; s <<= 1) v += __shfl_xor(v, s, 64);
      pd[mi][r] = v;
    }
  if (l15 == 0) {
    #pragma unroll
    for (int mi = 0; mi < 2; ++mi)
      #pragma unroll
      for (int r = 0; r < 4; ++r)
        ps[wn][wm * 32 + mi * 16 + l4 * 4 + r] = pd[mi][r];
  }
  __syncthreads();
  if (tid < 64) {
    int row = m0 + tid;
    if (row < M) {
      float v = ps[0][tid] + ps[1][tid];
      if (y == 0) pA[row] = v; else pB[row] = v;
    }
  }
}

// ---------------------------------------------------------------
// Crel (bf16) = rel @ W1[256:384,:] + b1 ;  pC = Crel . w2 (fp32)
// ---------------------------------------------------------------
__global__ __launch_bounds__(128) void crel_kernel(
    const float* __restrict__ rel, const float* __restrict__ W1,
    const float* __restrict__ b1, const float* __restrict__ w2,
    unsigned short* __restrict__ Crelbf, float* __restrict__ pC) {
  __shared__ float rs[128];
  __shared__ float red[128];
  int r = blockIdx.x;
  int d = threadIdx.x;
  rs[d] = rel[r * 128 + d];
  __syncthreads();
  float acc = b1[d];
  for (int k = 0; k < 128; ++k)
    acc = fmaf(rs[k], W1[(256 + k) * 128 + d], acc);
  Crelbf[r * 128 + d] = f2bf(acc);
  red[d] = acc * w2[d];
  __syncthreads();
  for (int s = 64; s > 0; s >>= 1) {
    if (d < s) red[d] += red[d + s];
    __syncthreads();
  }
  if (d == 0) pC[r] = red[0];
}

// ---------------------------------------------------------------
// CSR build
// ---------------------------------------------------------------
__global__ void hist_kernel(const int* __restrict__ dsts, int* __restrict__ deg, int E) {
  int i = blockIdx.x * 256 + threadIdx.x;
  if (i < E) atomicAdd(&deg[dsts[i]], 1);
}

__global__ __launch_bounds__(1024) void scan1(
    const int* __restrict__ deg, int* __restrict__ off,
    int* __restrict__ partial, int n) {
  __shared__ int sdata[1024];
  int t = threadIdx.x;
  int i = blockIdx.x * 1024 + t;
  int v = (i < n) ? deg[i] : 0;
  sdata[t] = v;
  __syncthreads();
  for (int s = 1; s < 1024; s <<= 1) {
    int add = (t >= s) ? sdata[t - s] : 0;
    __syncthreads();
    sdata[t] += add;
    __syncthreads();
  }
  if (i < n) off[i] = sdata[t] - v;
  if (t == 1023) partial[blockIdx.x] = sdata[1023];
}

__global__ __launch_bounds__(1024) void scan2(int* __restrict__ partial, int nb) {
  __shared__ int sdata[1024];
  int t = threadIdx.x;
  int v = (t < nb) ? partial[t] : 0;
  sdata[t] = v;
  __syncthreads();
  for (int s = 1; s < 1024; s <<= 1) {
    int add = (t >= s) ? sdata[t - s] : 0;
    __syncthreads();
    sdata[t] += add;
    __syncthreads();
  }
  if (t < nb) partial[t] = sdata[t] - v;
}

__global__ __launch_bounds__(1024) void scan3(
    int* __restrict__ off, int* __restrict__ pos,
    const int* __restrict__ partial, int n) {
  int i = blockIdx.x * 1024 + threadIdx.x;
  if (i < n) {
    int o = off[i] + partial[blockIdx.x];
    off[i] = o;
    pos[i] = o;
  }
}

__global__ void fill_perm(
    const int* __restrict__ srcs, const int* __restrict__ dsts,
    const int* __restrict__ types,
    const float* __restrict__ pA, const float* __restrict__ pB,
    const float* __restrict__ pC,
    int* __restrict__ pos,
    int* __restrict__ sperm, int* __restrict__ tperm,
    float* __restrict__ bperm, int E) {
  int i = blockIdx.x * 256 + threadIdx.x;
  if (i < E) {
    int dn = dsts[i];
    int s  = srcs[i];
    int t  = types[i];
    float b = pA[s] + pB[dn] + pC[t];
    b = b > 0.f ? b : SLOPE * b;
    int p = atomicAdd(&pos[dn], 1);
    sperm[p] = s;
    tperm[p] = t;
    bperm[p] = b;
  }
}

// ---------------------------------------------------------------
// Per-node softmax + weighted gather (A, Crel in bf16; packed loads).
// Lane owns cols {2*lane, 2*lane+1}.
// ---------------------------------------------------------------
__global__ __launch_bounds__(256) void aggregate(
    const int* __restrict__ off, const int* __restrict__ deg,
    const int* __restrict__ sperm, const int* __restrict__ tperm,
    const float* __restrict__ bperm,
    const unsigned short* __restrict__ Abf, const float* Bm,
    const unsigned short* __restrict__ Crelbf,
    float* out, int n_nodes) {
  int n = blockIdx.x * 4 + (threadIdx.x >> 6);
  if (n >= n_nodes) return;
  int lane = threadIdx.x & 63;
  int start = off[n];
  int dcnt = deg[n];
  size_t obase = (size_t)n * 128 + 2 * lane;
  if (dcnt == 0) {
    *(float2*)(out + obase) = (float2){0.f, 0.f};
    return;
  }
  float m = -1e30f;
  for (int i = lane; i < dcnt; i += 64) m = fmaxf(m, bperm[start + i]);
  #pragma unroll
  for (int s = 32; s; s >>= 1) m = fmaxf(m, __shfl_xor(m, s, 64));

  float acc0 = 0.f, acc1 = 0.f, S = 0.f;
  int i = 0;
  for (; i + 2 <= dcnt; i += 2) {
    int sa = sperm[start + i],     ta = tperm[start + i];
    int sb = sperm[start + i + 1], tb = tperm[start + i + 1];
    float exa = __expf(bperm[start + i] - m);
    float exb = __expf(bperm[start + i + 1] - m);
    unsigned int av = *(const unsigned int*)(Abf + (size_t)sa * 128 + 2 * lane);
    unsigned int cv = *(const unsigned int*)(Crelbf + ta * 128 + 2 * lane);
    unsigned int bv = *(const unsigned int*)(Abf + (size_t)sb * 128 + 2 * lane);
    unsigned int dv = *(const unsigned int*)(Crelbf + tb * 128 + 2 * lane);
    S += exa + exb;
    acc0 = fmaf(exa, bflo(av) + bflo(cv), acc0);
    acc1 = fmaf(exa, bfhi(av) + bfhi(cv), acc1);
    acc0 = fmaf(exb, bflo(bv) + bflo(dv), acc0);
    acc1 = fmaf(exb, bfhi(bv) + bfhi(dv), acc1);
  }
  if (i < dcnt) {
    int sa = sperm[start + i], ta = tperm[start + i];
    float exa = __expf(bperm[start + i] - m);
    unsigned int av = *(const unsigned int*)(Abf + (size_t)sa * 128 + 2 * lane);
    unsigned int cv = *(const unsigned int*)(Crelbf + ta * 128 + 2 * lane);
    S += exa;
    acc0 = fmaf(exa, bflo(av) + bflo(cv), acc0);
    acc1 = fmaf(exa, bfhi(av) + bfhi(cv), acc1);
  }
  float inv = 1.f / S;
  float2 rb = *(const float2*)(Bm + obase);
  float o0 = acc0 * inv + rb.x;
  float o1 = acc1 * inv + rb.y;
  o0 = o0 > 0.f ? o0 : SLOPE * o0;
  o1 = o1 > 0.f ? o1 : SLOPE * o1;
  *(float2*)(out + obase) = (float2){o0, o1};
}

extern "C" void kernel_launch(void* const* d_in, const int* in_sizes, int n_in,
                              void* d_out, int out_size, void* d_ws, size_t ws_size,
                              hipStream_t stream) {
  const float* x    = (const float*)d_in[0];
  const float* rel  = (const float*)d_in[1];
  const float* W1   = (const float*)d_in[2];
  const float* b1   = (const float*)d_in[3];
  const float* w2   = (const float*)d_in[4];
  const int* edge_index = (const int*)d_in[5];
  const int* edge_type  = (const int*)d_in[6];

  int n_nodes = in_sizes[0] / 128;
  int n_rel   = in_sizes[1] / 128;
  int E       = in_sizes[6];
  const int* srcs = edge_index;
  const int* dsts = edge_index + E;
  float* out = (float*)d_out;

  auto align256 = [](size_t v) { return (v + 255) & ~(size_t)255; };
  char* ws = (char*)d_ws;
  unsigned short* xb     = (unsigned short*)ws; ws += align256((size_t)n_nodes * 128 * 2);
  unsigned short* WT     = (unsigned short*)ws; ws += align256(256 * 128 * 2);
  unsigned short* Abf    = (unsigned short*)ws; ws += align256((size_t)n_nodes * 128 * 2);
  unsigned short* Crelbf = (unsigned short*)ws; ws += align256((size_t)n_rel * 128 * 2);
  float* pA    = (float*)ws; ws += align256((size_t)n_nodes * 4);
  float* pB    = (float*)ws; ws += align256((size_t)n_nodes * 4);
  float* pC    = (float*)ws; ws += align256((size_t)n_rel * 4);
  int* deg     = (int*)ws;   ws += align256((size_t)n_nodes * 4);
  int* off     = (int*)ws;   ws += align256((size_t)n_nodes * 4);
  int* pos     = (int*)ws;   ws += align256((size_t)n_nodes * 4);
  int* partial = (int*)ws;   ws += align256(1024 * 4);
  int* sperm   = (int*)ws;   ws += align256((size_t)E * 4);
  int* tperm   = (int*)ws;   ws += align256((size_t)E * 4);
  float* bperm = (float*)ws; ws += align256((size_t)E * 4);
  float* Bm    = out;

  hipMemsetAsync(deg, 0, (size_t)n_nodes * 4, stream);

  int total8 = n_nodes * 16;
  conv_x<<<(total8 + 255) / 256, 256, 0, stream>>>(x, xb, total8);
  conv_w<<<256, 128, 0, stream>>>(W1, WT);
  crel_kernel<<<n_rel, 128, 0, stream>>>(rel, W1, b1, w2, Crelbf, pC);

  dim3 ggrid((n_nodes + 63) / 64, 2);
  gemm_mfma<<<ggrid, 256, 0, stream>>>(xb, WT, w2, Abf, Bm, pA, pB, n_nodes);

  hist_kernel<<<(E + 255) / 256, 256, 0, stream>>>(dsts, deg, E);
  int nb = (n_nodes + 1023) / 1024;
  scan1<<<nb, 1024, 0, stream>>>(deg, off, partial, n_nodes);
  scan2<<<1, 1024, 0, stream>>>(partial, nb);
  scan3<<<nb, 1024, 0, stream>>>(off, pos, partial, n_nodes);
  fill_perm<<<(E + 255) / 256, 256, 0, stream>>>(
      srcs, dsts, edge_type, pA, pB, pC, pos, sperm, tperm, bperm, E);
  aggregate<<<(n_nodes + 3) / 4, 256, 0, stream>>>(
      off, deg, sperm, tperm, bperm, Abf, Bm, Crelbf, out, n_nodes);
}